// Round 7
// baseline (209.342 us; speedup 1.0000x reference)
//
#include <hip/hip_runtime.h>

typedef unsigned short u16;
typedef __bf16 bf16x8 __attribute__((ext_vector_type(8)));
typedef float f32x4 __attribute__((ext_vector_type(4)));

__device__ __forceinline__ u16 f2u(float f) {
    unsigned u = __builtin_bit_cast(unsigned, f);
    return (u16)((u + 0x7FFFu + ((u >> 16) & 1u)) >> 16);
}

__device__ __forceinline__ float u2f(u16 h) {
    return __builtin_bit_cast(float, (unsigned)h << 16);
}

__device__ __forceinline__ void glds16(const u16* g, u16* l) {
    __builtin_amdgcn_global_load_lds((const __attribute__((address_space(1))) unsigned int*)g,
                                     (__attribute__((address_space(3))) unsigned int*)l, 16, 0, 0);
}

// ---------------- prep: 5 weight transposes (tiled, coalesced) + x cvt + cnt zero ----------------

__global__ __launch_bounds__(256) void prep_k(
    const float* __restrict__ w0, const float* __restrict__ w1, const float* __restrict__ w2,
    const float* __restrict__ w3, const float* __restrict__ w4, const float* __restrict__ x,
    u16* __restrict__ o0, u16* __restrict__ o1, u16* __restrict__ o2,
    u16* __restrict__ o3, u16* __restrict__ o4, u16* __restrict__ xo,
    int* __restrict__ cnt, int xblocks, int nn) {
    int b = blockIdx.x, t = threadIdx.x;
    if (b < 144) {
        const float* in; u16* out; int R, C, tb;
        if (b < 16)       { in = w0; out = o0; R = 256; C = 256; tb = b; }
        else if (b < 64)  { in = w1; out = o1; R = 256; C = 768; tb = b - 16; }
        else if (b < 80)  { in = w2; out = o2; R = 256; C = 256; tb = b - 64; }
        else if (b < 112) { in = w3; out = o3; R = 256; C = 512; tb = b - 80; }
        else              { in = w4; out = o4; R = 512; C = 256; tb = b - 112; }
        int tcols = C >> 6;
        int tr = tb / tcols, tc = tb - tr * tcols;
        __shared__ float T[64][65];
        int i0 = t >> 6, j = t & 63;
#pragma unroll
        for (int p = 0; p < 16; p++) {
            int r = p * 4 + i0;
            T[r][j] = in[(long)(tr * 64 + r) * C + tc * 64 + j];
        }
        __syncthreads();
#pragma unroll
        for (int p = 0; p < 16; p++) {
            int c = p * 4 + i0;
            out[(long)(tc * 64 + c) * R + tr * 64 + j] = f2u(T[j][c]);
        }
    } else if (b < 144 + xblocks) {
        long base = (long)(b - 144) * 4096;
#pragma unroll
        for (int p = 0; p < 4; p++) {
            long idx = base + p * 1024 + t * 4;
            float4 v = *(const float4*)&x[idx];
            unsigned lo = (unsigned)f2u(v.x) | ((unsigned)f2u(v.y) << 16);
            unsigned hi = (unsigned)f2u(v.z) | ((unsigned)f2u(v.w) << 16);
            *(uint2*)&xo[idx] = uint2{lo, hi};
        }
    } else {
        int i = (b - 144 - xblocks) * 256 + t;
        if (i < nn) cnt[i] = 0;
    }
}

__global__ void count_k(const int* __restrict__ ei, int E, int* __restrict__ cnt) {
    int e = blockIdx.x * 256 + threadIdx.x;
    if (e < E) atomicAdd(&cnt[ei[E + e]], 1);
}

__global__ __launch_bounds__(256) void scan_k(const int* __restrict__ cnt, int* __restrict__ offs,
                                              int* __restrict__ cur, float* __restrict__ dinv) {
    __shared__ int sums[256];
    int t = threadIdx.x;
    int base = t * 16;
    int loc[16]; int s = 0;
#pragma unroll
    for (int i = 0; i < 16; i++) { loc[i] = s; s += cnt[base + i]; }
    sums[t] = s;
    __syncthreads();
    for (int off = 1; off < 256; off <<= 1) {
        int v = (t >= off) ? sums[t - off] : 0;
        __syncthreads();
        sums[t] += v;
        __syncthreads();
    }
    int ex = (t == 0) ? 0 : sums[t - 1];
#pragma unroll
    for (int i = 0; i < 16; i++) {
        int o = ex + loc[i];
        offs[base + i] = o; cur[base + i] = o;
        dinv[base + i] = rsqrtf((float)(cnt[base + i] + 1));
    }
}

__global__ void scatter_k(const int* __restrict__ ei, int E, int* __restrict__ cur, int* __restrict__ srcs) {
    int e = blockIdx.x * 256 + threadIdx.x;
    if (e < E) {
        int s = ei[e], d = ei[E + e];
        int p = atomicAdd(&cur[d], 1);
        srcs[p] = s;
    }
}

// ---------------- LN helper ----------------

__device__ __forceinline__ void block_ln_stats(float v, float& mu, float& rstd) {
    float s1 = v, s2 = v * v;
#pragma unroll
    for (int m = 1; m < 64; m <<= 1) { s1 += __shfl_xor(s1, m, 64); s2 += __shfl_xor(s2, m, 64); }
    __shared__ float r1[4], r2[4];
    int lane = threadIdx.x & 63, w = threadIdx.x >> 6;
    if (lane == 0) { r1[w] = s1; r2[w] = s2; }
    __syncthreads();
    s1 = r1[0] + r1[1] + r1[2] + r1[3];
    s2 = r2[0] + r2[1] + r2[2] + r2[3];
    mu = s1 * (1.0f / 256.0f);
    float var = s2 * (1.0f / 256.0f) - mu * mu;
    rstd = rsqrtf(var + 1e-5f);
}

__global__ __launch_bounds__(256) void ln_k(const float* __restrict__ a, const float* __restrict__ b,
                                            const float* __restrict__ g, const float* __restrict__ be,
                                            float* __restrict__ out, u16* __restrict__ outbf) {
    int n = blockIdx.x, d = threadIdx.x;
    long i = (long)n * 256 + d;
    float v = a[i] + b[i];
    float mu, rs;
    block_ln_stats(v, mu, rs);
    float y = (v - mu) * rs * g[d] + be[d];
    out[i] = y;
    if (outbf) outbf[i] = f2u(y);
}

// ---------------- GCN aggregation (CSR gather of bf16 h, 4-way unrolled) + fused LN1 ----------------

__global__ __launch_bounds__(256) void gcn_agg_ln_k(
    const u16* __restrict__ h, const float* __restrict__ x,
    const int* __restrict__ srcs, const int* __restrict__ offs, const int* __restrict__ cnt,
    const float* __restrict__ dinv, const float* __restrict__ bg,
    const float* __restrict__ g, const float* __restrict__ be,
    float* __restrict__ x1, u16* __restrict__ x1bf) {
    int n = blockIdx.x, d = threadIdx.x;
    int c = cnt[n], st = offs[n];
    float dn = dinv[n];
    float agg = u2f(h[(long)n * 256 + d]) * dn;  // self loop
    int e = 0;
    for (; e + 4 <= c; e += 4) {
        int s0 = srcs[st + e], s1 = srcs[st + e + 1], s2 = srcs[st + e + 2], s3 = srcs[st + e + 3];
        float a0 = u2f(h[(long)s0 * 256 + d]) * dinv[s0];
        float a1 = u2f(h[(long)s1 * 256 + d]) * dinv[s1];
        float a2 = u2f(h[(long)s2 * 256 + d]) * dinv[s2];
        float a3 = u2f(h[(long)s3 * 256 + d]) * dinv[s3];
        agg += (a0 + a1) + (a2 + a3);
    }
    for (; e < c; e++) {
        int s = srcs[st + e];
        agg += u2f(h[(long)s * 256 + d]) * dinv[s];
    }
    float v = x[(long)n * 256 + d] + dn * agg + bg[d];
    float mu, rs;
    block_ln_stats(v, mu, rs);
    float y = (v - mu) * rs * g[d] + be[d];
    x1[(long)n * 256 + d] = y;
    x1bf[(long)n * 256 + d] = f2u(y);
}

// ---------------- GEMM 32x64 tile (grid 2x vs 64x64), whole-K staging, ONE barrier/round ----------------
// block: A 32 rows (16 KiB/round), B 64 cols (32 KiB/round) -> 48 KiB LDS, 3 blocks/CU.
// wave tile 16x32. EPI 0: f32. EPI 1: qkv (q scaled 0.125*log2e, v transposed). 2: relu->bf16. 3: bf16.

template <int EPI>
__global__ __launch_bounds__(256) void gemm_k(
    const u16* __restrict__ A, const u16* __restrict__ Bt,
    const float* __restrict__ bias, void* __restrict__ outp,
    int M, int N, int K) {
    __shared__ __align__(16) u16 As[32 * 256];   // 16 KiB
    __shared__ __align__(16) u16 Bs[64 * 256];   // 32 KiB
    int tid = threadIdx.x;
    int lane = tid & 63, w = tid >> 6;
    int l15 = lane & 15, quad = lane >> 4, l7 = l15 & 7;
    int m0 = blockIdx.x * 32, n0 = blockIdx.y * 64;
    int wm = (w >> 1) * 16, wn = (w & 1) * 32;
    f32x4 acc[2];
    acc[0] = f32x4{0.f, 0.f, 0.f, 0.f};
    acc[1] = f32x4{0.f, 0.f, 0.f, 0.f};

    int rA = (wm + l15) * 256;
    int rB0 = (wn + l15) * 256, rB1 = (wn + 16 + l15) * 256;

    for (int kb = 0; kb < K; kb += 256) {
        if (kb) __syncthreads();
#pragma unroll
        for (int i = 0; i < 4; i++) {
            int s = i * 256 + tid;
            int j = s >> 5, c = (s & 31) ^ (j & 7);
            glds16(A + (long)(m0 + j) * K + kb + c * 8, &As[s * 8]);
        }
#pragma unroll
        for (int i = 0; i < 8; i++) {
            int s = i * 256 + tid;
            int j = s >> 5, c = (s & 31) ^ (j & 7);
            glds16(Bt + (long)(n0 + j) * K + kb + c * 8, &Bs[s * 8]);
        }
        __syncthreads();
#pragma unroll
        for (int step = 0; step < 8; step++) {
            int d8 = (((step << 2) + quad) ^ l7) << 3;
            bf16x8 af0 = *(const bf16x8*)&As[rA + d8];
            bf16x8 bf0 = *(const bf16x8*)&Bs[rB0 + d8];
            bf16x8 bf1 = *(const bf16x8*)&Bs[rB1 + d8];
            acc[0] = __builtin_amdgcn_mfma_f32_16x16x32_bf16(af0, bf0, acc[0], 0, 0, 0);
            acc[1] = __builtin_amdgcn_mfma_f32_16x16x32_bf16(af0, bf1, acc[1], 0, 0, 0);
        }
    }

#pragma unroll
    for (int nf = 0; nf < 2; nf++) {
        int col = n0 + wn + nf * 16 + l15;
        float bv = bias ? bias[col] : 0.0f;
#pragma unroll
        for (int r = 0; r < 4; r++) {
            int row = m0 + wm + quad * 4 + r;
            float v = acc[nf][r] + bv;
            if (EPI == 0) {
                ((float*)outp)[(long)row * N + col] = v;
            } else if (EPI == 1) {
                u16* q = (u16*)outp;
                u16* kk = q + (long)M * 256;
                u16* vt = kk + (long)M * 256;
                if (col < 256) {
                    q[(((col >> 6) * (long)M) + row) * 64 + (col & 63)] = f2u(v * 0.180336884f);
                } else if (col < 512) {
                    int c = col - 256;
                    kk[(((c >> 6) * (long)M) + row) * 64 + (c & 63)] = f2u(v);
                } else {
                    int c = col - 512;
                    vt[((c >> 6) * 64 + (c & 63)) * (long)M + row] = f2u(v);
                }
            } else if (EPI == 2) {
                ((u16*)outp)[(long)row * N + col] = f2u(v > 0.f ? v : 0.f);
            } else {
                ((u16*)outp)[(long)row * N + col] = f2u(v);
            }
        }
    }
}

// ---------------- Flash attention, split-K partials, LDS-staged K/V, S^T + fast exp2 ----------------

__global__ __launch_bounds__(256) void attn_k(const u16* __restrict__ qg, const u16* __restrict__ kg,
                                              const u16* __restrict__ vtg, float* __restrict__ po,
                                              float* __restrict__ pl, int N, int S) {
    int tid = threadIdx.x;
    int w = tid >> 6, lane = tid & 63, l15 = lane & 15, quad = lane >> 4;
    int lid = blockIdx.x + 64 * blockIdx.y + 256 * blockIdx.z;
    int hs = lid & 15;            // (head, split) -> XCD hs&7
    int hh = hs & 3, sp = hs >> 2, qb = lid >> 4;
    int q0 = qb * 64 + w * 16;
    int kbeg = sp * (N / S);
    int nit = (N / S) / 64;
    const u16* qh = qg + (long)hh * N * 64;
    const u16* kh = kg + (long)hh * N * 64;
    const u16* vh = vtg + (long)hh * 64 * N;

    __shared__ __align__(16) u16 KV[2][2][4096];  // 32 KiB
    __shared__ __align__(16) u16 P[4][1024];      //  8 KiB
    u16* Pw = &P[w][0];

    int s0 = tid, j0 = s0 >> 3, c0s = ((s0 & 7) ^ (j0 & 7)) * 8;
    int s1 = tid + 256, j1 = s1 >> 3, c1s = ((s1 & 7) ^ (j1 & 7)) * 8;
    const u16* kp0 = kh + (long)(kbeg + j0) * 64 + c0s;
    const u16* kp1 = kh + (long)(kbeg + j1) * 64 + c1s;
    const u16* vp0 = vh + (long)j0 * N + kbeg + c0s;
    const u16* vp1 = vh + (long)j1 * N + kbeg + c1s;
    u16* lk0[2] = {&KV[0][0][s0 * 8], &KV[1][0][s0 * 8]};
    u16* lk1[2] = {&KV[0][0][s1 * 8], &KV[1][0][s1 * 8]};
    u16* lv0[2] = {&KV[0][1][s0 * 8], &KV[1][1][s0 * 8]};
    u16* lv1[2] = {&KV[0][1][s1 * 8], &KV[1][1][s1 * 8]};

    int lo3 = l15 & 7;
    int c0 = (quad ^ lo3) * 8;
    int c1 = c0 ^ 32;
    int ps = lo3 << 1;
    int pw0 = l15 * 64 + (((quad << 1) ^ ps) << 2);
    int pw1 = l15 * 64 + (((8 + (quad << 1)) ^ ps) << 2);
    int pca[4];
#pragma unroll
    for (int nt = 0; nt < 4; nt++) pca[nt] = l15 * 64 + (((nt * 4 + quad) ^ ps) << 2);

    bf16x8 aq0 = *(const bf16x8*)(qh + (long)(q0 + l15) * 64 + quad * 8);
    bf16x8 aq1 = *(const bf16x8*)(qh + (long)(q0 + l15) * 64 + 32 + quad * 8);
    bf16x8 ones;
#pragma unroll
    for (int i = 0; i < 8; i++) ones[i] = (__bf16)1.0f;

    f32x4 o[4];
#pragma unroll
    for (int dn = 0; dn < 4; dn++) o[dn] = f32x4{0.f, 0.f, 0.f, 0.f};
    f32x4 accl = f32x4{0.f, 0.f, 0.f, 0.f};

    glds16(kp0, lk0[0]); glds16(kp1, lk1[0]);
    glds16(vp0, lv0[0]); glds16(vp1, lv1[0]);
    kp0 += 4096; kp1 += 4096; vp0 += 64; vp1 += 64;

    for (int it = 0; it < nit; it++) {
        __syncthreads();
        if (it + 1 < nit) {
            int nb = (it + 1) & 1;
            glds16(kp0, lk0[nb]); glds16(kp1, lk1[nb]);
            glds16(vp0, lv0[nb]); glds16(vp1, lv1[nb]);
            kp0 += 4096; kp1 += 4096; vp0 += 64; vp1 += 64;
        }
        const u16* Kc = &KV[it & 1][0][0];
        const u16* Vc = &KV[it & 1][1][0];
#pragma unroll
        for (int nt = 0; nt < 4; nt++) {
            const u16* Kr = Kc + (nt * 16 + l15) * 64;
            bf16x8 kf0 = *(const bf16x8*)(Kr + c0);
            bf16x8 kf1 = *(const bf16x8*)(Kr + c1);
            f32x4 s = f32x4{0.f, 0.f, 0.f, 0.f};
            s = __builtin_amdgcn_mfma_f32_16x16x32_bf16(kf0, aq0, s, 0, 0, 0);  // C[key][query]
            s = __builtin_amdgcn_mfma_f32_16x16x32_bf16(kf1, aq1, s, 0, 0, 0);
            unsigned u0 = (unsigned)((int)(s[0] * 8388608.0f) + 1064992209);
            unsigned u1 = (unsigned)((int)(s[1] * 8388608.0f) + 1064992209);
            unsigned u2 = (unsigned)((int)(s[2] * 8388608.0f) + 1064992209);
            unsigned u3 = (unsigned)((int)(s[3] * 8388608.0f) + 1064992209);
            unsigned pk01 = __builtin_amdgcn_perm(u1, u0, 0x07060302u);
            unsigned pk23 = __builtin_amdgcn_perm(u3, u2, 0x07060302u);
            *(uint2*)&Pw[pca[nt]] = uint2{pk01, pk23};
        }
        bf16x8 pa0 = *(const bf16x8*)&Pw[pw0];
        bf16x8 pa1 = *(const bf16x8*)&Pw[pw1];
        accl = __builtin_amdgcn_mfma_f32_16x16x32_bf16(pa0, ones, accl, 0, 0, 0);
        accl = __builtin_amdgcn_mfma_f32_16x16x32_bf16(pa1, ones, accl, 0, 0, 0);
#pragma unroll
        for (int dn = 0; dn < 4; dn++) {
            const u16* Vr = Vc + (dn * 16 + l15) * 64;
            bf16x8 v0 = *(const bf16x8*)(Vr + c0);
            bf16x8 v1 = *(const bf16x8*)(Vr + c1);
            o[dn] = __builtin_amdgcn_mfma_f32_16x16x32_bf16(pa0, v0, o[dn], 0, 0, 0);
            o[dn] = __builtin_amdgcn_mfma_f32_16x16x32_bf16(pa1, v1, o[dn], 0, 0, 0);
        }
    }

    long pbase = ((long)(sp * 4 + hh)) * N;
#pragma unroll
    for (int dn = 0; dn < 4; dn++)
#pragma unroll
        for (int r = 0; r < 4; r++) {
            int row = q0 + quad * 4 + r;
            po[(pbase + row) * 64 + dn * 16 + l15] = o[dn][r];
        }
    if (l15 == 0) {
#pragma unroll
        for (int r = 0; r < 4; r++) pl[pbase + q0 + quad * 4 + r] = accl[r];
    }
}

__global__ __launch_bounds__(256) void attn_comb_k(const float* __restrict__ po, const float* __restrict__ pl,
                                                   u16* __restrict__ xo, int N, int S) {
    int n = blockIdx.x, c = threadIdx.x;
    int hh = c >> 6, d = c & 63;
    float osum = 0.f, lsum = 0.f;
    for (int s = 0; s < S; s++) {
        osum += po[(((long)(s * 4 + hh)) * N + n) * 64 + d];
        lsum += pl[((long)(s * 4 + hh)) * N + n];
    }
    xo[(long)n * 256 + c] = f2u(osum / lsum);
}

// ---------------- launcher ----------------

extern "C" void kernel_launch(void* const* d_in, const int* in_sizes, int n_in,
                              void* d_out, int out_size, void* d_ws, size_t ws_size,
                              hipStream_t stream) {
    const float* x    = (const float*)d_in[0];
    const int*   ei   = (const int*)d_in[1];
    const float* Wg   = (const float*)d_in[2];
    const float* bg   = (const float*)d_in[3];
    const float* Wqkv = (const float*)d_in[4];
    const float* bqkv = (const float*)d_in[5];
    const float* Wo   = (const float*)d_in[6];
    const float* bo   = (const float*)d_in[7];
    const float* g1l  = (const float*)d_in[8];
    const float* b1l  = (const float*)d_in[9];
    const float* g1a  = (const float*)d_in[10];
    const float* b1a  = (const float*)d_in[11];
    const float* W1   = (const float*)d_in[12];
    const float* bf1  = (const float*)d_in[13];
    const float* W2   = (const float*)d_in[14];
    const float* bf2  = (const float*)d_in[15];
    const float* g2   = (const float*)d_in[16];
    const float* b2   = (const float*)d_in[17];
    float* out = (float*)d_out;

    int N = in_sizes[0] / 256;  // 4096
    int E = in_sizes[1] / 2;    // 131072
    const int S = 4;

    char* p = (char*)d_ws;
    auto alloc = [&](size_t bytes) { void* r = (void*)p; p += (bytes + 255) & ~(size_t)255; return r; };
    u16*   wg_t   = (u16*)alloc((size_t)256 * 256 * 2);
    u16*   wqkv_t = (u16*)alloc((size_t)256 * 768 * 2);
    u16*   wo_t   = (u16*)alloc((size_t)256 * 256 * 2);
    u16*   w1_t   = (u16*)alloc((size_t)512 * 256 * 2);
    u16*   w2_t   = (u16*)alloc((size_t)256 * 512 * 2);
    u16*   xbf    = (u16*)alloc((size_t)N * 256 * 2);
    u16*   h      = (u16*)alloc((size_t)N * 256 * 2);
    int*   cnt    = (int*)alloc((size_t)N * 4);
    int*   offs   = (int*)alloc((size_t)N * 4);
    int*   cur    = (int*)alloc((size_t)N * 4);
    float* dinv   = (float*)alloc((size_t)N * 4);
    int*   srcs   = (int*)alloc((size_t)E * 4);
    float* x1     = (float*)alloc((size_t)N * 256 * 4);
    u16*   x1bf   = (u16*)alloc((size_t)N * 256 * 2);
    u16*   qkv    = (u16*)alloc((size_t)3 * N * 256 * 2);
    u16*   xattn  = (u16*)alloc((size_t)N * 256 * 2);
    float* attno  = (float*)alloc((size_t)N * 256 * 4);
    float* x2     = (float*)alloc((size_t)N * 256 * 4);
    u16*   x2bf   = (u16*)alloc((size_t)N * 256 * 2);
    u16*   ffn1   = (u16*)alloc((size_t)N * 512 * 2);
    float* ffno   = (float*)alloc((size_t)N * 256 * 4);
    float* po     = (float*)alloc((size_t)S * 4 * N * 64 * 4);
    float* pl     = (float*)alloc((size_t)S * 4 * N * 4);

    dim3 b256(256);

    int xblocks = (N * 256) / 4096;
    int cblocks = (N + 255) / 256;
    prep_k<<<144 + xblocks + cblocks, b256, 0, stream>>>(Wg, Wqkv, Wo, W1, W2, x,
                                                         wg_t, wqkv_t, wo_t, w1_t, w2_t, xbf,
                                                         cnt, xblocks, N);

    count_k<<<(E + 255) / 256, b256, 0, stream>>>(ei, E, cnt);
    scan_k<<<1, b256, 0, stream>>>(cnt, offs, cur, dinv);
    scatter_k<<<(E + 255) / 256, b256, 0, stream>>>(ei, E, cur, srcs);

    gemm_k<3><<<dim3(N / 32, 4), b256, 0, stream>>>(xbf, wg_t, nullptr, h, N, 256, 256);
    gcn_agg_ln_k<<<N, b256, 0, stream>>>(h, x, srcs, offs, cnt, dinv, bg, g1l, b1l, x1, x1bf);

    gemm_k<1><<<dim3(N / 32, 12), b256, 0, stream>>>(x1bf, wqkv_t, bqkv, qkv, N, 768, 256);
    attn_k<<<dim3(N / 64, 4, S), b256, 0, stream>>>(qkv, qkv + (size_t)N * 256, qkv + (size_t)2 * N * 256,
                                                    po, pl, N, S);
    attn_comb_k<<<N, b256, 0, stream>>>(po, pl, xattn, N, S);
    gemm_k<0><<<dim3(N / 32, 4), b256, 0, stream>>>(xattn, wo_t, bo, attno, N, 256, 256);
    ln_k<<<N, b256, 0, stream>>>(x1, attno, g1a, b1a, x2, x2bf);

    gemm_k<2><<<dim3(N / 32, 8), b256, 0, stream>>>(x2bf, w1_t, bf1, ffn1, N, 512, 256);
    gemm_k<0><<<dim3(N / 32, 4), b256, 0, stream>>>(ffn1, w2_t, bf2, ffno, N, 256, 512);
    ln_k<<<N, b256, 0, stream>>>(x2, ffno, g2, b2, out, nullptr);
}

// Round 9
// 208.741 us; speedup vs baseline: 1.0029x; 1.0029x over previous
//
#include <hip/hip_runtime.h>

typedef unsigned short u16;
typedef __bf16 bf16x8 __attribute__((ext_vector_type(8)));
typedef float f32x4 __attribute__((ext_vector_type(4)));

__device__ __forceinline__ u16 f2u(float f) {
    unsigned u = __builtin_bit_cast(unsigned, f);
    return (u16)((u + 0x7FFFu + ((u >> 16) & 1u)) >> 16);
}

__device__ __forceinline__ float u2f(u16 h) {
    return __builtin_bit_cast(float, (unsigned)h << 16);
}

__device__ __forceinline__ void glds16(const u16* g, u16* l) {
    __builtin_amdgcn_global_load_lds((const __attribute__((address_space(1))) unsigned int*)g,
                                     (__attribute__((address_space(3))) unsigned int*)l, 16, 0, 0);
}

// ---------------- prep: 5 weight transposes (tiled, coalesced) + x cvt + cnt zero ----------------

__global__ __launch_bounds__(256) void prep_k(
    const float* __restrict__ w0, const float* __restrict__ w1, const float* __restrict__ w2,
    const float* __restrict__ w3, const float* __restrict__ w4, const float* __restrict__ x,
    u16* __restrict__ o0, u16* __restrict__ o1, u16* __restrict__ o2,
    u16* __restrict__ o3, u16* __restrict__ o4, u16* __restrict__ xo,
    int* __restrict__ cnt, int xblocks, int nn) {
    int b = blockIdx.x, t = threadIdx.x;
    if (b < 144) {
        const float* in; u16* out; int R, C, tb;
        if (b < 16)       { in = w0; out = o0; R = 256; C = 256; tb = b; }
        else if (b < 64)  { in = w1; out = o1; R = 256; C = 768; tb = b - 16; }
        else if (b < 80)  { in = w2; out = o2; R = 256; C = 256; tb = b - 64; }
        else if (b < 112) { in = w3; out = o3; R = 256; C = 512; tb = b - 80; }
        else              { in = w4; out = o4; R = 512; C = 256; tb = b - 112; }
        int tcols = C >> 6;
        int tr = tb / tcols, tc = tb - tr * tcols;
        __shared__ float T[64][65];
        int i0 = t >> 6, j = t & 63;
#pragma unroll
        for (int p = 0; p < 16; p++) {
            int r = p * 4 + i0;
            T[r][j] = in[(long)(tr * 64 + r) * C + tc * 64 + j];
        }
        __syncthreads();
#pragma unroll
        for (int p = 0; p < 16; p++) {
            int c = p * 4 + i0;
            out[(long)(tc * 64 + c) * R + tr * 64 + j] = f2u(T[j][c]);
        }
    } else if (b < 144 + xblocks) {
        long base = (long)(b - 144) * 4096;
#pragma unroll
        for (int p = 0; p < 4; p++) {
            long idx = base + p * 1024 + t * 4;
            float4 v = *(const float4*)&x[idx];
            unsigned lo = (unsigned)f2u(v.x) | ((unsigned)f2u(v.y) << 16);
            unsigned hi = (unsigned)f2u(v.z) | ((unsigned)f2u(v.w) << 16);
            *(uint2*)&xo[idx] = uint2{lo, hi};
        }
    } else {
        int i = (b - 144 - xblocks) * 256 + t;
        if (i < nn) cnt[i] = 0;
    }
}

__global__ void count_k(const int* __restrict__ ei, int E, int* __restrict__ cnt) {
    int e = blockIdx.x * 256 + threadIdx.x;
    if (e < E) atomicAdd(&cnt[ei[E + e]], 1);
}

__global__ __launch_bounds__(256) void scan_k(const int* __restrict__ cnt, int* __restrict__ offs,
                                              int* __restrict__ cur, float* __restrict__ dinv) {
    __shared__ int sums[256];
    int t = threadIdx.x;
    int base = t * 16;
    int loc[16]; int s = 0;
#pragma unroll
    for (int i = 0; i < 16; i++) { loc[i] = s; s += cnt[base + i]; }
    sums[t] = s;
    __syncthreads();
    for (int off = 1; off < 256; off <<= 1) {
        int v = (t >= off) ? sums[t - off] : 0;
        __syncthreads();
        sums[t] += v;
        __syncthreads();
    }
    int ex = (t == 0) ? 0 : sums[t - 1];
#pragma unroll
    for (int i = 0; i < 16; i++) {
        int o = ex + loc[i];
        offs[base + i] = o; cur[base + i] = o;
        dinv[base + i] = rsqrtf((float)(cnt[base + i] + 1));
    }
}

// ---------------- LN helper ----------------

__device__ __forceinline__ void block_ln_stats(float v, float& mu, float& rstd) {
    float s1 = v, s2 = v * v;
#pragma unroll
    for (int m = 1; m < 64; m <<= 1) { s1 += __shfl_xor(s1, m, 64); s2 += __shfl_xor(s2, m, 64); }
    __shared__ float r1[4], r2[4];
    int lane = threadIdx.x & 63, w = threadIdx.x >> 6;
    if (lane == 0) { r1[w] = s1; r2[w] = s2; }
    __syncthreads();
    s1 = r1[0] + r1[1] + r1[2] + r1[3];
    s2 = r2[0] + r2[1] + r2[2] + r2[3];
    mu = s1 * (1.0f / 256.0f);
    float var = s2 * (1.0f / 256.0f) - mu * mu;
    rstd = rsqrtf(var + 1e-5f);
}

__global__ __launch_bounds__(256) void ln_k(const float* __restrict__ a, const float* __restrict__ b,
                                            const float* __restrict__ g, const float* __restrict__ be,
                                            float* __restrict__ out, u16* __restrict__ outbf) {
    int n = blockIdx.x, d = threadIdx.x;
    long i = (long)n * 256 + d;
    float v = a[i] + b[i];
    float mu, rs;
    block_ln_stats(v, mu, rs);
    float y = (v - mu) * rs * g[d] + be[d];
    out[i] = y;
    if (outbf) outbf[i] = f2u(y);
}

// ---------------- GCN aggregation (CSR gather of bf16 h) + fused LN1 ----------------

__global__ __launch_bounds__(256) void gcn_agg_ln_k(
    const u16* __restrict__ h, const float* __restrict__ x,
    const int* __restrict__ srcs, const int* __restrict__ offs, const int* __restrict__ cnt,
    const float* __restrict__ dinv, const float* __restrict__ bg,
    const float* __restrict__ g, const float* __restrict__ be,
    float* __restrict__ x1, u16* __restrict__ x1bf) {
    int n = blockIdx.x, d = threadIdx.x;
    int c = cnt[n], st = offs[n];
    float dn = dinv[n];
    float agg = u2f(h[(long)n * 256 + d]) * dn;  // self loop
    int e = 0;
    for (; e + 4 <= c; e += 4) {
        int s0 = srcs[st + e], s1 = srcs[st + e + 1], s2 = srcs[st + e + 2], s3 = srcs[st + e + 3];
        float a0 = u2f(h[(long)s0 * 256 + d]) * dinv[s0];
        float a1 = u2f(h[(long)s1 * 256 + d]) * dinv[s1];
        float a2 = u2f(h[(long)s2 * 256 + d]) * dinv[s2];
        float a3 = u2f(h[(long)s3 * 256 + d]) * dinv[s3];
        agg += (a0 + a1) + (a2 + a3);
    }
    for (; e < c; e++) {
        int s = srcs[st + e];
        agg += u2f(h[(long)s * 256 + d]) * dinv[s];
    }
    float v = x[(long)n * 256 + d] + dn * agg + bg[d];
    float mu, rs;
    block_ln_stats(v, mu, rs);
    float y = (v - mu) * rs * g[d] + be[d];
    x1[(long)n * 256 + d] = y;
    x1bf[(long)n * 256 + d] = f2u(y);
}

// ---------------- GEMM 64x64, whole-K LDS staging, ONE barrier/round; optional fused scatter ----------------
// EPI 0: f32. EPI 1: qkv (q scaled 0.125*log2e, v transposed). 2: relu->bf16. 3: bf16.
// FUSE_SCAT: extra grid.y slice does the CSR scatter (independent work, saves a launch).

template <int EPI, bool FUSE_SCAT = false>
__global__ __launch_bounds__(256) void gemm_k(
    const u16* __restrict__ A, const u16* __restrict__ Bt,
    const float* __restrict__ bias, void* __restrict__ outp,
    int M, int N, int K,
    const int* __restrict__ ei = nullptr, int E = 0,
    int* __restrict__ cur = nullptr, int* __restrict__ srcs = nullptr) {
    __shared__ __align__(16) u16 As[64 * 256];   // 32 KiB
    __shared__ __align__(16) u16 Bs[64 * 256];   // 32 KiB
    if (FUSE_SCAT && blockIdx.y == gridDim.y - 1) {
        int nth = gridDim.x * 256;
        for (int e = blockIdx.x * 256 + threadIdx.x; e < E; e += nth) {
            int s = ei[e], d = ei[E + e];
            int p = atomicAdd(&cur[d], 1);
            srcs[p] = s;
        }
        return;
    }
    int tid = threadIdx.x;
    int lane = tid & 63, w = tid >> 6;
    int l15 = lane & 15, quad = lane >> 4, l7 = l15 & 7;
    int m0 = blockIdx.x * 64, n0 = blockIdx.y * 64;
    int wm = (w >> 1) * 32, wn = (w & 1) * 32;
    f32x4 acc[2][2];
#pragma unroll
    for (int i = 0; i < 2; i++)
#pragma unroll
        for (int j = 0; j < 2; j++) acc[i][j] = f32x4{0.f, 0.f, 0.f, 0.f};

    int rA0 = (wm + l15) * 256, rA1 = (wm + 16 + l15) * 256;
    int rB0 = (wn + l15) * 256, rB1 = (wn + 16 + l15) * 256;

    for (int kb = 0; kb < K; kb += 256) {
        if (kb) __syncthreads();
#pragma unroll
        for (int i = 0; i < 8; i++) {
            int s = i * 256 + tid;
            int j = s >> 5, c = (s & 31) ^ (j & 7);
            glds16(A + (long)(m0 + j) * K + kb + c * 8, &As[s * 8]);
            glds16(Bt + (long)(n0 + j) * K + kb + c * 8, &Bs[s * 8]);
        }
        __syncthreads();
#pragma unroll
        for (int step = 0; step < 8; step++) {
            int d8 = (((step << 2) + quad) ^ l7) << 3;
            bf16x8 af0 = *(const bf16x8*)&As[rA0 + d8];
            bf16x8 af1 = *(const bf16x8*)&As[rA1 + d8];
            bf16x8 bf0 = *(const bf16x8*)&Bs[rB0 + d8];
            bf16x8 bf1 = *(const bf16x8*)&Bs[rB1 + d8];
            acc[0][0] = __builtin_amdgcn_mfma_f32_16x16x32_bf16(af0, bf0, acc[0][0], 0, 0, 0);
            acc[0][1] = __builtin_amdgcn_mfma_f32_16x16x32_bf16(af0, bf1, acc[0][1], 0, 0, 0);
            acc[1][0] = __builtin_amdgcn_mfma_f32_16x16x32_bf16(af1, bf0, acc[1][0], 0, 0, 0);
            acc[1][1] = __builtin_amdgcn_mfma_f32_16x16x32_bf16(af1, bf1, acc[1][1], 0, 0, 0);
        }
    }

#pragma unroll
    for (int nf = 0; nf < 2; nf++) {
        int col = n0 + wn + nf * 16 + l15;
        float bv = bias ? bias[col] : 0.0f;
#pragma unroll
        for (int mf = 0; mf < 2; mf++) {
#pragma unroll
            for (int r = 0; r < 4; r++) {
                int row = m0 + wm + mf * 16 + quad * 4 + r;
                float v = acc[mf][nf][r] + bv;
                if (EPI == 0) {
                    ((float*)outp)[(long)row * N + col] = v;
                } else if (EPI == 1) {
                    u16* q = (u16*)outp;
                    u16* kk = q + (long)M * 256;
                    u16* vt = kk + (long)M * 256;
                    if (col < 256) {
                        q[(((col >> 6) * (long)M) + row) * 64 + (col & 63)] = f2u(v * 0.180336884f);
                    } else if (col < 512) {
                        int c = col - 256;
                        kk[(((c >> 6) * (long)M) + row) * 64 + (c & 63)] = f2u(v);
                    } else {
                        int c = col - 512;
                        vt[((c >> 6) * 64 + (c & 63)) * (long)M + row] = f2u(v);
                    }
                } else if (EPI == 2) {
                    ((u16*)outp)[(long)row * N + col] = f2u(v > 0.f ? v : 0.f);
                } else {
                    ((u16*)outp)[(long)row * N + col] = f2u(v);
                }
            }
        }
    }
}

// ---------------- Flash attention, split-K partials (S=8), LDS-staged K/V, S^T + fast exp2 ----------------
// grid (N/64, 4, S) = 2048 blocks; decode: hs = lid & 31 (head 2b + split 3b), qb = lid >> 5.

__global__ __launch_bounds__(256) void attn_k(const u16* __restrict__ qg, const u16* __restrict__ kg,
                                              const u16* __restrict__ vtg, float* __restrict__ po,
                                              float* __restrict__ pl, int N, int S) {
    int tid = threadIdx.x;
    int w = tid >> 6, lane = tid & 63, l15 = lane & 15, quad = lane >> 4;
    int lid = blockIdx.x + 64 * blockIdx.y + 256 * blockIdx.z;
    int hs = lid & 31;            // (head, split) combo; low 3 bits spread XCDs
    int hh = hs & 3, sp = hs >> 2, qb = lid >> 5;
    int q0 = qb * 64 + w * 16;
    int kbeg = sp * (N / S);
    int nit = (N / S) / 64;
    const u16* qh = qg + (long)hh * N * 64;
    const u16* kh = kg + (long)hh * N * 64;
    const u16* vh = vtg + (long)hh * 64 * N;

    __shared__ __align__(16) u16 KV[2][2][4096];  // 32 KiB
    __shared__ __align__(16) u16 P[4][1024];      //  8 KiB
    u16* Pw = &P[w][0];

    int s0 = tid, j0 = s0 >> 3, c0s = ((s0 & 7) ^ (j0 & 7)) * 8;
    int s1 = tid + 256, j1 = s1 >> 3, c1s = ((s1 & 7) ^ (j1 & 7)) * 8;
    const u16* kp0 = kh + (long)(kbeg + j0) * 64 + c0s;
    const u16* kp1 = kh + (long)(kbeg + j1) * 64 + c1s;
    const u16* vp0 = vh + (long)j0 * N + kbeg + c0s;
    const u16* vp1 = vh + (long)j1 * N + kbeg + c1s;
    u16* lk0[2] = {&KV[0][0][s0 * 8], &KV[1][0][s0 * 8]};
    u16* lk1[2] = {&KV[0][0][s1 * 8], &KV[1][0][s1 * 8]};
    u16* lv0[2] = {&KV[0][1][s0 * 8], &KV[1][1][s0 * 8]};
    u16* lv1[2] = {&KV[0][1][s1 * 8], &KV[1][1][s1 * 8]};

    int lo3 = l15 & 7;
    int c0 = (quad ^ lo3) * 8;
    int c1 = c0 ^ 32;
    int ps = lo3 << 1;
    int pw0 = l15 * 64 + (((quad << 1) ^ ps) << 2);
    int pw1 = l15 * 64 + (((8 + (quad << 1)) ^ ps) << 2);
    int pca[4];
#pragma unroll
    for (int nt = 0; nt < 4; nt++) pca[nt] = l15 * 64 + (((nt * 4 + quad) ^ ps) << 2);

    bf16x8 aq0 = *(const bf16x8*)(qh + (long)(q0 + l15) * 64 + quad * 8);
    bf16x8 aq1 = *(const bf16x8*)(qh + (long)(q0 + l15) * 64 + 32 + quad * 8);
    bf16x8 ones;
#pragma unroll
    for (int i = 0; i < 8; i++) ones[i] = (__bf16)1.0f;

    f32x4 o[4];
#pragma unroll
    for (int dn = 0; dn < 4; dn++) o[dn] = f32x4{0.f, 0.f, 0.f, 0.f};
    f32x4 accl = f32x4{0.f, 0.f, 0.f, 0.f};

    glds16(kp0, lk0[0]); glds16(kp1, lk1[0]);
    glds16(vp0, lv0[0]); glds16(vp1, lv1[0]);
    kp0 += 4096; kp1 += 4096; vp0 += 64; vp1 += 64;

    for (int it = 0; it < nit; it++) {
        __syncthreads();
        if (it + 1 < nit) {
            int nb = (it + 1) & 1;
            glds16(kp0, lk0[nb]); glds16(kp1, lk1[nb]);
            glds16(vp0, lv0[nb]); glds16(vp1, lv1[nb]);
            kp0 += 4096; kp1 += 4096; vp0 += 64; vp1 += 64;
        }
        const u16* Kc = &KV[it & 1][0][0];
        const u16* Vc = &KV[it & 1][1][0];
#pragma unroll
        for (int nt = 0; nt < 4; nt++) {
            const u16* Kr = Kc + (nt * 16 + l15) * 64;
            bf16x8 kf0 = *(const bf16x8*)(Kr + c0);
            bf16x8 kf1 = *(const bf16x8*)(Kr + c1);
            f32x4 s = f32x4{0.f, 0.f, 0.f, 0.f};
            s = __builtin_amdgcn_mfma_f32_16x16x32_bf16(kf0, aq0, s, 0, 0, 0);  // C[key][query]
            s = __builtin_amdgcn_mfma_f32_16x16x32_bf16(kf1, aq1, s, 0, 0, 0);
            unsigned u0 = (unsigned)((int)(s[0] * 8388608.0f) + 1064992209);
            unsigned u1 = (unsigned)((int)(s[1] * 8388608.0f) + 1064992209);
            unsigned u2 = (unsigned)((int)(s[2] * 8388608.0f) + 1064992209);
            unsigned u3 = (unsigned)((int)(s[3] * 8388608.0f) + 1064992209);
            unsigned pk01 = __builtin_amdgcn_perm(u1, u0, 0x07060302u);
            unsigned pk23 = __builtin_amdgcn_perm(u3, u2, 0x07060302u);
            *(uint2*)&Pw[pca[nt]] = uint2{pk01, pk23};
        }
        bf16x8 pa0 = *(const bf16x8*)&Pw[pw0];
        bf16x8 pa1 = *(const bf16x8*)&Pw[pw1];
        accl = __builtin_amdgcn_mfma_f32_16x16x32_bf16(pa0, ones, accl, 0, 0, 0);
        accl = __builtin_amdgcn_mfma_f32_16x16x32_bf16(pa1, ones, accl, 0, 0, 0);
#pragma unroll
        for (int dn = 0; dn < 4; dn++) {
            const u16* Vr = Vc + (dn * 16 + l15) * 64;
            bf16x8 v0 = *(const bf16x8*)(Vr + c0);
            bf16x8 v1 = *(const bf16x8*)(Vr + c1);
            o[dn] = __builtin_amdgcn_mfma_f32_16x16x32_bf16(pa0, v0, o[dn], 0, 0, 0);
            o[dn] = __builtin_amdgcn_mfma_f32_16x16x32_bf16(pa1, v1, o[dn], 0, 0, 0);
        }
    }

    long pbase = ((long)(sp * 4 + hh)) * N;
#pragma unroll
    for (int dn = 0; dn < 4; dn++)
#pragma unroll
        for (int r = 0; r < 4; r++) {
            int row = q0 + quad * 4 + r;
            po[(pbase + row) * 64 + dn * 16 + l15] = o[dn][r];
        }
    if (l15 == 0) {
#pragma unroll
        for (int r = 0; r < 4; r++) pl[pbase + q0 + quad * 4 + r] = accl[r];
    }
}

__global__ __launch_bounds__(256) void attn_comb_k(const float* __restrict__ po, const float* __restrict__ pl,
                                                   u16* __restrict__ xo, int N, int S) {
    int n = blockIdx.x, c = threadIdx.x;
    int hh = c >> 6, d = c & 63;
    float osum = 0.f, lsum = 0.f;
    for (int s = 0; s < S; s++) {
        osum += po[(((long)(s * 4 + hh)) * N + n) * 64 + d];
        lsum += pl[((long)(s * 4 + hh)) * N + n];
    }
    xo[(long)n * 256 + c] = f2u(osum / lsum);
}

// ---------------- launcher ----------------

extern "C" void kernel_launch(void* const* d_in, const int* in_sizes, int n_in,
                              void* d_out, int out_size, void* d_ws, size_t ws_size,
                              hipStream_t stream) {
    const float* x    = (const float*)d_in[0];
    const int*   ei   = (const int*)d_in[1];
    const float* Wg   = (const float*)d_in[2];
    const float* bg   = (const float*)d_in[3];
    const float* Wqkv = (const float*)d_in[4];
    const float* bqkv = (const float*)d_in[5];
    const float* Wo   = (const float*)d_in[6];
    const float* bo   = (const float*)d_in[7];
    const float* g1l  = (const float*)d_in[8];
    const float* b1l  = (const float*)d_in[9];
    const float* g1a  = (const float*)d_in[10];
    const float* b1a  = (const float*)d_in[11];
    const float* W1   = (const float*)d_in[12];
    const float* bf1  = (const float*)d_in[13];
    const float* W2   = (const float*)d_in[14];
    const float* bf2  = (const float*)d_in[15];
    const float* g2   = (const float*)d_in[16];
    const float* b2   = (const float*)d_in[17];
    float* out = (float*)d_out;

    int N = in_sizes[0] / 256;  // 4096
    int E = in_sizes[1] / 2;    // 131072
    const int S = 8;

    char* p = (char*)d_ws;
    auto alloc = [&](size_t bytes) { void* r = (void*)p; p += (bytes + 255) & ~(size_t)255; return r; };
    u16*   wg_t   = (u16*)alloc((size_t)256 * 256 * 2);
    u16*   wqkv_t = (u16*)alloc((size_t)256 * 768 * 2);
    u16*   wo_t   = (u16*)alloc((size_t)256 * 256 * 2);
    u16*   w1_t   = (u16*)alloc((size_t)512 * 256 * 2);
    u16*   w2_t   = (u16*)alloc((size_t)256 * 512 * 2);
    u16*   xbf    = (u16*)alloc((size_t)N * 256 * 2);
    u16*   h      = (u16*)alloc((size_t)N * 256 * 2);
    int*   cnt    = (int*)alloc((size_t)N * 4);
    int*   offs   = (int*)alloc((size_t)N * 4);
    int*   cur    = (int*)alloc((size_t)N * 4);
    float* dinv   = (float*)alloc((size_t)N * 4);
    int*   srcs   = (int*)alloc((size_t)E * 4);
    float* x1     = (float*)alloc((size_t)N * 256 * 4);
    u16*   x1bf   = (u16*)alloc((size_t)N * 256 * 2);
    u16*   qkv    = (u16*)alloc((size_t)3 * N * 256 * 2);
    u16*   xattn  = (u16*)alloc((size_t)N * 256 * 2);
    float* attno  = (float*)alloc((size_t)N * 256 * 4);
    float* x2     = (float*)alloc((size_t)N * 256 * 4);
    u16*   x2bf   = (u16*)alloc((size_t)N * 256 * 2);
    u16*   ffn1   = (u16*)alloc((size_t)N * 512 * 2);
    float* ffno   = (float*)alloc((size_t)N * 256 * 4);
    float* po     = (float*)alloc((size_t)S * 4 * N * 64 * 4);
    float* pl     = (float*)alloc((size_t)S * 4 * N * 4);

    dim3 b256(256);

    int xblocks = (N * 256) / 4096;
    int cblocks = (N + 255) / 256;
    prep_k<<<144 + xblocks + cblocks, b256, 0, stream>>>(Wg, Wqkv, Wo, W1, W2, x,
                                                         wg_t, wqkv_t, wo_t, w1_t, w2_t, xbf,
                                                         cnt, xblocks, N);

    count_k<<<(E + 255) / 256, b256, 0, stream>>>(ei, E, cnt);
    scan_k<<<1, b256, 0, stream>>>(cnt, offs, cur, dinv);

    // h-GEMM + fused CSR scatter (extra grid.y slice)
    gemm_k<3, true><<<dim3(N / 64, 5), b256, 0, stream>>>(xbf, wg_t, nullptr, h, N, 256, 256,
                                                          ei, E, cur, srcs);
    gcn_agg_ln_k<<<N, b256, 0, stream>>>(h, x, srcs, offs, cnt, dinv, bg, g1l, b1l, x1, x1bf);

    gemm_k<1><<<dim3(N / 64, 12), b256, 0, stream>>>(x1bf, wqkv_t, bqkv, qkv, N, 768, 256);
    attn_k<<<dim3(N / 64, 4, S), b256, 0, stream>>>(qkv, qkv + (size_t)N * 256, qkv + (size_t)2 * N * 256,
                                                    po, pl, N, S);
    attn_comb_k<<<N, b256, 0, stream>>>(po, pl, xattn, N, S);
    gemm_k<0><<<dim3(N / 64, 4), b256, 0, stream>>>(xattn, wo_t, bo, attno, N, 256, 256);
    ln_k<<<N, b256, 0, stream>>>(x1, attno, g1a, b1a, x2, x2bf);

    gemm_k<2><<<dim3(N / 64, 8), b256, 0, stream>>>(x2bf, w1_t, bf1, ffn1, N, 512, 256);
    gemm_k<0><<<dim3(N / 64, 4), b256, 0, stream>>>(ffn1, w2_t, bf2, ffno, N, 256, 512);
    ln_k<<<N, b256, 0, stream>>>(x2, ffno, g2, b2, out, nullptr);
}